// Round 20
// baseline (191.223 us; speedup 1.0000x reference)
//
#include <hip/hip_runtime.h>
#include <hip/hip_bf16.h>
#include <hip/hip_fp8.h>

// Problem constants (fixed by the reference)
constexpr int Nn  = 100000;   // nodes
constexpr int Ee  = 1600000;  // edges
constexpr int FIN = 128;      // input features
constexpr int Hh  = 32;       // hidden
constexpr int Cc  = 10;       // classes
constexpr int Gg  = 256;      // graphs

// Two-level counting sort: ranges of 256 nodes, chunks of 8192 edges.
constexpr int RSH  = 8;                          // range shift (256 nodes)
constexpr int NR   = (Nn + 255) >> RSH;          // 391 ranges
constexpr int CHSZ = 8192;                       // edges per chunk
constexpr int NCH  = (Ee + CHSZ - 1) / CHSZ;     // 196 chunks
constexpr int DB   = (Nn + 1023) / 1024;         // 98 blocks for degree perm

typedef __attribute__((ext_vector_type(8))) short bf16x8;
typedef __attribute__((ext_vector_type(4))) float f32x4;

__device__ __forceinline__ void atomAddF(float* p, float v) {
    unsafeAtomicAdd(p, v);    // HW global_atomic_add_f32 on gfx950
}

__device__ __forceinline__ short f2bfbits(float v) {
    __hip_bfloat16 h = __float2bfloat16(v);
    return __builtin_bit_cast(short, h);
}

// fp8 e4m3 storage (OCP on gfx950): table rows are 32 B (32 x fp8).
__device__ __forceinline__ void fp8pair(unsigned short u, float& lo, float& hi) {
#if __has_builtin(__builtin_amdgcn_cvt_f32_fp8)
    lo = __builtin_amdgcn_cvt_f32_fp8((int)u, 0);
    hi = __builtin_amdgcn_cvt_f32_fp8((int)u, 1);
#else
    __hip_fp8_e4m3 a, b;
    a.__x = (unsigned char)(u & 0xff);
    b.__x = (unsigned char)(u >> 8);
    lo = (float)a; hi = (float)b;
#endif
}
__device__ __forceinline__ unsigned char ftofp8(float f) {
    __hip_fp8_e4m3 v(f);
    return (unsigned char)v.__x;
}

// ---------- S1: per-chunk histogram over node ranges ----------
__global__ __launch_bounds__(512) void k_count(const int* __restrict__ dst,
                                               int* __restrict__ M) {
    __shared__ int hist[NR];
    int c = blockIdx.x;
    for (int i = threadIdx.x; i < NR; i += 512) hist[i] = 0;
    __syncthreads();
    int e0 = c * CHSZ, e1 = min(e0 + CHSZ, Ee);
    const int4* d4 = reinterpret_cast<const int4*>(dst + e0);
    int n4 = (e1 - e0) >> 2;
    for (int i = threadIdx.x; i < n4; i += 512) {
        int4 d = d4[i];
        atomicAdd(&hist[d.x >> RSH], 1);
        atomicAdd(&hist[d.y >> RSH], 1);
        atomicAdd(&hist[d.z >> RSH], 1);
        atomicAdd(&hist[d.w >> RSH], 1);
    }
    __syncthreads();
    for (int i = threadIdx.x; i < NR; i += 512) M[c * NR + i] = hist[i];
}

// ---------- S2a: per-range exclusive scan over chunks (in place), totals -> T
__global__ __launch_bounds__(256) void k_scanM(int* __restrict__ M,
                                               int* __restrict__ T) {
    __shared__ int sh[256];
    int t = threadIdx.x, r = blockIdx.x;
    int v = (t < NCH) ? M[t * NR + r] : 0;
    sh[t] = v;
    __syncthreads();
    for (int off = 1; off < 256; off <<= 1) {
        int x = (t >= off) ? sh[t - off] : 0;
        __syncthreads();
        sh[t] += x;
        __syncthreads();
    }
    if (t < NCH) M[t * NR + r] = sh[t] - v;   // exclusive
    if (t == 255) T[r] = sh[255];
}

// ---------- S2b: exclusive scan of range totals -> R (R[NR] = Ee) ----------
__global__ __launch_bounds__(512) void k_scanT(const int* __restrict__ T,
                                               int* __restrict__ R) {
    __shared__ int sh[512];
    int t = threadIdx.x;
    int v = (t < NR) ? T[t] : 0;
    sh[t] = v;
    __syncthreads();
    for (int off = 1; off < 512; off <<= 1) {
        int x = (t >= off) ? sh[t - off] : 0;
        __syncthreads();
        sh[t] += x;
        __syncthreads();
    }
    if (t < NR) R[t] = sh[t] - v;
    if (t == 511) R[NR] = sh[511];
}

// ---------- S3: scatter packed (localdst<<17 | src) into range bucket ----------
__global__ __launch_bounds__(512) void k_bucket(const int* __restrict__ src,
                                                const int* __restrict__ dst,
                                                const int* __restrict__ M,
                                                const int* __restrict__ R,
                                                unsigned* __restrict__ bucket) {
    __shared__ int cur[NR];
    int c = blockIdx.x;
    for (int i = threadIdx.x; i < NR; i += 512) cur[i] = M[c * NR + i] + R[i];
    __syncthreads();
    int e0 = c * CHSZ, e1 = min(e0 + CHSZ, Ee);
    const int4* d4 = reinterpret_cast<const int4*>(dst + e0);
    const int4* s4 = reinterpret_cast<const int4*>(src + e0);
    int n4 = (e1 - e0) >> 2;
    for (int i = threadIdx.x; i < n4; i += 512) {
        int4 d = d4[i];
        int4 s = s4[i];
        int sl;
        sl = atomicAdd(&cur[d.x >> RSH], 1); bucket[sl] = ((unsigned)(d.x & 255) << 17) | (unsigned)s.x;
        sl = atomicAdd(&cur[d.y >> RSH], 1); bucket[sl] = ((unsigned)(d.y & 255) << 17) | (unsigned)s.y;
        sl = atomicAdd(&cur[d.z >> RSH], 1); bucket[sl] = ((unsigned)(d.z & 255) << 17) | (unsigned)s.z;
        sl = atomicAdd(&cur[d.w >> RSH], 1); bucket[sl] = ((unsigned)(d.w & 255) << 17) | (unsigned)s.w;
    }
}

// ---------- S4: per-range CSR build + deg + dinv + rowptr ----------
__global__ __launch_bounds__(512) void k_build(const unsigned* __restrict__ bucket,
                                               const int* __restrict__ R,
                                               int* __restrict__ csr,
                                               int* __restrict__ rowptr,
                                               int* __restrict__ deg,
                                               float* __restrict__ dinv) {
    __shared__ int hist[256];
    __shared__ int scn[256];
    __shared__ int cur[256];
    int t = threadIdx.x, r = blockIdx.x;
    int lo = r << RSH;
    int cnt = min(256, Nn - lo);
    int b0 = R[r], b1 = R[r + 1];
    if (t < 256) hist[t] = 0;
    __syncthreads();
    for (int i = b0 + t; i < b1; i += 512) {
        unsigned e = bucket[i];
        atomicAdd(&hist[e >> 17], 1);
    }
    __syncthreads();
    int hv = (t < 256) ? hist[t] : 0;
    if (t < 256) scn[t] = hv;
    __syncthreads();
    for (int off = 1; off < 256; off <<= 1) {
        int x = 0;
        if (t < 256 && t >= off) x = scn[t - off];
        __syncthreads();
        if (t < 256) scn[t] += x;
        __syncthreads();
    }
    if (t < cnt) {
        int base = b0 + (scn[t] - hv);   // exclusive within range + range start
        rowptr[lo + t] = base;
        deg[lo + t] = hv;
        dinv[lo + t] = rsqrtf((float)hv + 1.0f);
        cur[t] = base;
    }
    __syncthreads();
    for (int i = b0 + t; i < b1; i += 512) {
        unsigned e = bucket[i];
        int sl = atomicAdd(&cur[e >> 17], 1);
        csr[sl] = (int)(e & 0x1FFFFu);
    }
}

// ---------- degree-binned permutation (equalize per-wave gather rounds) ----
// Counting sort of node ids by degree. M2 reuses M (dead after k_bucket);
// perm reuses bucket (dead after k_build). Waves in k_aggemm then serve 4
// nodes of ~equal degree -> E[max rounds] drops 1.90 -> ~1.44.
__global__ __launch_bounds__(256) void k_dhist(const int* __restrict__ deg,
                                               int* __restrict__ M2) {
    __shared__ int h[256];
    int b = blockIdx.x, t = threadIdx.x;
    h[t] = 0;
    __syncthreads();
    int n0 = b * 1024, n1 = min(n0 + 1024, Nn);
    for (int n = n0 + t; n < n1; n += 256)
        atomicAdd(&h[min(deg[n], 255)], 1);
    __syncthreads();
    M2[b * 256 + t] = h[t];
}

__global__ __launch_bounds__(256) void k_dscan(int* __restrict__ M2) {
    __shared__ int tot[256];
    int t = threadIdx.x;                 // t = degree bin
    int s = 0;
    for (int b = 0; b < DB; ++b) {       // exclusive scan over blocks (coalesced)
        int v = M2[b * 256 + t];
        M2[b * 256 + t] = s;
        s += v;
    }
    tot[t] = s;
    __syncthreads();
    int v = tot[t];
    __syncthreads();
    for (int off = 1; off < 256; off <<= 1) {
        int x = (t >= off) ? tot[t - off] : 0;
        __syncthreads();
        tot[t] += x;
        __syncthreads();
    }
    int base = tot[t] - v;               // exclusive bin base
    for (int b = 0; b < DB; ++b) M2[b * 256 + t] += base;
}

__global__ __launch_bounds__(256) void k_dperm(const int* __restrict__ deg,
                                               const int* __restrict__ M2,
                                               int* __restrict__ perm) {
    __shared__ int cur[256];
    int b = blockIdx.x, t = threadIdx.x;
    cur[t] = M2[b * 256 + t];
    __syncthreads();
    int n0 = b * 1024, n1 = min(n0 + 1024, Nn);
    for (int n = n0 + t; n < n1; n += 256) {
        int pos = atomicAdd(&cur[min(deg[n], 255)], 1);
        perm[pos] = n;
    }
}

// ---------- layer-1 GEMM via bf16 MFMA (no LDS, no syncthreads), fp8 out ----
constexpr int TM = 64;
__global__ __launch_bounds__(256) void k_gemm128(const float* __restrict__ x,
                                                 const float* __restrict__ W,
                                                 const float* __restrict__ dinv,
                                                 unsigned char* __restrict__ hls) {
    int tid  = threadIdx.x;
    int wave = tid >> 6;
    int lane = tid & 63;
    int lrow = lane & 15;
    int koct = lane >> 4;                       // 0..3
    int row0 = blockIdx.x * TM + wave * 16;
    int gr   = row0 + lrow;
    int grc  = (gr < Nn) ? gr : (Nn - 1);       // clamped load row

    // B fragments: 2 col-tiles x 4 K-steps, lane holds W[kb+j][ct*16+lrow]
    bf16x8 bfrag[2][4];
#pragma unroll
    for (int s = 0; s < 4; ++s) {
        int kb = s * 32 + koct * 8;
#pragma unroll
        for (int ct = 0; ct < 2; ++ct) {
            int col = ct * 16 + lrow;
            bf16x8 bb;
#pragma unroll
            for (int j = 0; j < 8; ++j) bb[j] = f2bfbits(W[(kb + j) * Hh + col]);
            bfrag[ct][s] = bb;
        }
    }

    f32x4 acc0 = {0.f, 0.f, 0.f, 0.f};
    f32x4 acc1 = {0.f, 0.f, 0.f, 0.f};
    const float4* xrow = reinterpret_cast<const float4*>(x + (size_t)grc * FIN);
#pragma unroll
    for (int s = 0; s < 4; ++s) {
        int kb = s * 32 + koct * 8;             // f4 index = kb/4
        float4 v0 = xrow[kb / 4];
        float4 v1 = xrow[kb / 4 + 1];
        bf16x8 af;
        af[0] = f2bfbits(v0.x); af[1] = f2bfbits(v0.y);
        af[2] = f2bfbits(v0.z); af[3] = f2bfbits(v0.w);
        af[4] = f2bfbits(v1.x); af[5] = f2bfbits(v1.y);
        af[6] = f2bfbits(v1.z); af[7] = f2bfbits(v1.w);
        acc0 = __builtin_amdgcn_mfma_f32_16x16x32_bf16(af, bfrag[0][s], acc0, 0, 0, 0);
        acc1 = __builtin_amdgcn_mfma_f32_16x16x32_bf16(af, bfrag[1][s], acc1, 0, 0, 0);
    }

    // write back: row = row0 + (lane>>4)*4 + r, cols lrow and lrow+16 (fp8)
    int crow0 = row0 + koct * 4;
#pragma unroll
    for (int r = 0; r < 4; ++r) {
        int rr = crow0 + r;
        if (rr < Nn) {
            float d = dinv[rr];
            hls[(size_t)rr * Hh + lrow]      = ftofp8(acc0[r] * d);
            hls[(size_t)rr * Hh + 16 + lrow] = ftofp8(acc1[r] * d);
        } else if (rr == Nn) {                  // zero pad row
            hls[(size_t)Nn * Hh + lrow]      = 0;
            hls[(size_t)Nn * Hh + 16 + lrow] = 0;
        }
    }
}

// ---------- fused aggregation + next-layer GEMM (fp8 tables) ----------
// 16 lanes/node, each lane owns cols (2l, 2l+1) as one packed fp8x2 ushort.
// MLP=16; masked lanes gather the zeroed pad row Nn. Table = 3.2 MB -> fits
// each XCD's 4 MB L2. Plain cached loads (round 14: nontemporal breaks L2
// retention). Nodes assigned via degree-sorted perm: a wave's 4 nodes have
// ~equal degree -> no wasted max-rounds (round 20 lever).
__global__ __launch_bounds__(256) void k_aggemm(const unsigned char* __restrict__ hls,
                                                const int* __restrict__ csr,
                                                const int* __restrict__ rowptr,
                                                const int* __restrict__ deg,
                                                const float* __restrict__ dinv,
                                                const float* __restrict__ b,
                                                const float* __restrict__ Wn,
                                                const int* __restrict__ perm,
                                                unsigned char* __restrict__ hout) {
    __shared__ float ws[Hh * Hh];
    int tid = threadIdx.x;
    ws[tid]       = Wn[tid];
    ws[tid + 256] = Wn[tid + 256];
    ws[tid + 512] = Wn[tid + 512];
    ws[tid + 768] = Wn[tid + 768];
    if (blockIdx.x == 0 && tid < 16)   // zero pad row of output table
        reinterpret_cast<unsigned short*>(hout)[Nn * 16 + tid] = 0;
    __syncthreads();
    int n = perm[blockIdx.x * 16 + (tid >> 4)];   // broadcast within group
    int l = tid & 15;
    const unsigned short* h16 = reinterpret_cast<const unsigned short*>(hls);
    int beg = rowptr[n];
    int end = beg + deg[n];
    float a0 = 0.f, a1 = 0.f;
    for (int i = beg; i < end; i += 16) {
        int idx[16];
#pragma unroll
        for (int j = 0; j < 16; ++j) {
            int k = i + j;
            int c = csr[k];                 // csr padded by 16 -> in-bounds
            idx[j] = (k < end) ? c : Nn;    // Nn = zeroed pad row
        }
        unsigned short v[16];
#pragma unroll
        for (int j = 0; j < 16; ++j) v[j] = h16[idx[j] * 16 + l];
#pragma unroll
        for (int j = 0; j < 16; ++j) {
            float lo, hi;
            fp8pair(v[j], lo, hi);
            a0 += lo;
            a1 += hi;
        }
    }
    float di = dinv[n];
    float s0, s1;
    fp8pair(h16[(size_t)n * 16 + l], s0, s1);
    int c0 = 2 * l, c1 = 2 * l + 1;
    float h0 = fmaxf(fmaf(di, a0 + s0, b[c0]), 0.f);
    float h1 = fmaxf(fmaf(di, a1 + s1, b[c1]), 0.f);
    // micro-GEMM: o[c] = sum_k h_k * Wn[k][c]; h_{2m},h_{2m+1} live in lane m
    float o0 = 0.f, o1 = 0.f;
#pragma unroll
    for (int m = 0; m < 16; ++m) {
        float hk0 = __shfl(h0, m, 16);
        float hk1 = __shfl(h1, m, 16);
        o0 = fmaf(hk0, ws[(2 * m) * Hh + c0], o0);
        o0 = fmaf(hk1, ws[(2 * m + 1) * Hh + c0], o0);
        o1 = fmaf(hk0, ws[(2 * m) * Hh + c1], o1);
        o1 = fmaf(hk1, ws[(2 * m + 1) * Hh + c1], o1);
    }
    unsigned short packed = (unsigned short)ftofp8(o0 * di) |
                            ((unsigned short)ftofp8(o1 * di) << 8);
    reinterpret_cast<unsigned short*>(hout)[(size_t)n * 16 + l] = packed;
}

// ---------- final aggregation fused with mean-pool (fp8 table in) ----------
// Natural node order (pool fusion needs sorted batch) — unchanged.
__global__ __launch_bounds__(256) void k_aggpool(const unsigned char* __restrict__ hls,
                                                 const int* __restrict__ csr,
                                                 const int* __restrict__ rowptr,
                                                 const int* __restrict__ deg,
                                                 const float* __restrict__ dinv,
                                                 const float* __restrict__ b,
                                                 const int* __restrict__ batch,
                                                 float* __restrict__ pooled,
                                                 int* __restrict__ cnt) {
    __shared__ float hsh[16 * 34];   // stride 34 to spread banks
    __shared__ int   gsh[16];
    int tid = threadIdx.x;
    int nd = tid >> 4;
    int n = blockIdx.x * 16 + nd;
    int l = tid & 15;
    const unsigned short* h16 = reinterpret_cast<const unsigned short*>(hls);
    int beg = rowptr[n];
    int end = beg + deg[n];
    float a0 = 0.f, a1 = 0.f;
    for (int i = beg; i < end; i += 16) {
        int idx[16];
#pragma unroll
        for (int j = 0; j < 16; ++j) {
            int k = i + j;
            int c = csr[k];
            idx[j] = (k < end) ? c : Nn;
        }
        unsigned short v[16];
#pragma unroll
        for (int j = 0; j < 16; ++j) v[j] = h16[idx[j] * 16 + l];
#pragma unroll
        for (int j = 0; j < 16; ++j) {
            float lo, hi;
            fp8pair(v[j], lo, hi);
            a0 += lo;
            a1 += hi;
        }
    }
    float di = dinv[n];
    float s0, s1;
    fp8pair(h16[(size_t)n * 16 + l], s0, s1);
    float h0 = fmaxf(fmaf(di, a0 + s0, b[2 * l]), 0.f);
    float h1 = fmaxf(fmaf(di, a1 + s1, b[2 * l + 1]), 0.f);
    hsh[nd * 34 + 2 * l]     = h0;
    hsh[nd * 34 + 2 * l + 1] = h1;
    if (l == 0) gsh[nd] = batch[n];
    __syncthreads();
    if (tid < 32) {           // segmented flush: col = tid
        int col = tid;
        float acc = 0.f;
        int gcur = gsh[0];
#pragma unroll
        for (int k = 0; k < 16; ++k) {
            int g = gsh[k];
            if (g != gcur) {
                atomAddF(&pooled[gcur * Hh + col], acc);
                acc = 0.f; gcur = g;
            }
            acc += hsh[k * 34 + col];
        }
        atomAddF(&pooled[gcur * Hh + col], acc);
    } else if (tid == 32) {   // node counts
        int gcur = gsh[0], run = 0;
#pragma unroll
        for (int k = 0; k < 16; ++k) {
            int g = gsh[k];
            if (g != gcur) { atomicAdd(&cnt[gcur], run); run = 0; gcur = g; }
            run++;
        }
        atomicAdd(&cnt[gcur], run);
    }
}

// ---------- MLP head + log_softmax ----------
__global__ __launch_bounds__(256) void k_head(const float* __restrict__ pooled,
                                              const int* __restrict__ cnt,
                                              const float* __restrict__ Wf1,
                                              const float* __restrict__ bf1,
                                              const float* __restrict__ Wf2,
                                              const float* __restrict__ bf2,
                                              float* __restrict__ out) {
    __shared__ float w1[Hh * Hh];
    __shared__ float w2[Hh * Cc];
    __shared__ float sb1[Hh];
    __shared__ float sb2[Cc];
    int tid = threadIdx.x;
    w1[tid] = Wf1[tid]; w1[tid + 256] = Wf1[tid + 256];
    w1[tid + 512] = Wf1[tid + 512]; w1[tid + 768] = Wf1[tid + 768];
    for (int i = tid; i < Hh * Cc; i += 256) w2[i] = Wf2[i];
    if (tid < Hh) sb1[tid] = bf1[tid];
    if (tid < Cc) sb2[tid] = bf2[tid];
    __syncthreads();

    int g = tid;
    float inv = 1.0f / fmaxf((float)cnt[g], 1.0f);
    float p[Hh];
#pragma unroll
    for (int c = 0; c < Hh; ++c) p[c] = pooled[g * Hh + c] * inv;
    float h1[Hh];
#pragma unroll
    for (int j = 0; j < Hh; ++j) {
        float acc = sb1[j];
#pragma unroll
        for (int k = 0; k < Hh; ++k) acc = fmaf(p[k], w1[k * Hh + j], acc);
        h1[j] = fmaxf(acc, 0.f);
    }
    float lg[Cc];
#pragma unroll
    for (int j = 0; j < Cc; ++j) {
        float acc = sb2[j];
#pragma unroll
        for (int k = 0; k < Hh; ++k) acc = fmaf(h1[k], w2[k * Cc + j], acc);
        lg[j] = acc;
    }
    float m = lg[0];
#pragma unroll
    for (int j = 1; j < Cc; ++j) m = fmaxf(m, lg[j]);
    float s = 0.f;
#pragma unroll
    for (int j = 0; j < Cc; ++j) s += __expf(lg[j] - m);
    float lse = m + __logf(s);
#pragma unroll
    for (int j = 0; j < Cc; ++j) out[g * Cc + j] = lg[j] - lse;
}

extern "C" void kernel_launch(void* const* d_in, const int* in_sizes, int n_in,
                              void* d_out, int out_size, void* d_ws, size_t ws_size,
                              hipStream_t stream) {
    const float* x    = (const float*)d_in[0];
    const int*   ei   = (const int*)d_in[1];   // [2, E] -> src = ei, dst = ei + E
    const int*   batch= (const int*)d_in[2];
    const float* W1   = (const float*)d_in[3];
    const float* b1   = (const float*)d_in[4];
    const float* W2   = (const float*)d_in[5];
    const float* b2   = (const float*)d_in[6];
    const float* W3   = (const float*)d_in[7];
    const float* b3   = (const float*)d_in[8];
    const float* W4   = (const float*)d_in[9];
    const float* b4   = (const float*)d_in[10];
    const float* Wf1  = (const float*)d_in[11];
    const float* bf1  = (const float*)d_in[12];
    const float* Wf2  = (const float*)d_in[13];
    const float* bf2  = (const float*)d_in[14];
    float* out = (float*)d_out;

    const int* src = ei;
    const int* dst = ei + Ee;

    // Workspace layout (8B-aligned first). Feature tables are fp8 (32 B/row,
    // 3.2 MB -> L2-resident per XCD) with a zeroed pad row at index Nn.
    // perm aliases bucket (dead after k_build); M2 aliases M (dead after
    // k_bucket).
    char* ws = (char*)d_ws;
    unsigned* bucket = (unsigned*)ws; ws += sizeof(unsigned) * Ee;           // 6.4 MB
    unsigned char* hl   = (unsigned char*)ws; ws += (size_t)(Nn + 1) * Hh;   // 3.2 MB
    unsigned char* hbuf = (unsigned char*)ws; ws += (size_t)(Nn + 1) * Hh;   // 3.2 MB
    int*   csr    = (int*)ws;     ws += sizeof(int) * (Ee + 16);             // +16 pad
    int*   M      = (int*)ws;     ws += sizeof(int) * NCH * NR;              // 306 KB
    int*   T      = (int*)ws;     ws += sizeof(int) * NR;
    int*   R      = (int*)ws;     ws += sizeof(int) * (NR + 1);
    int*   rowptr = (int*)ws;     ws += sizeof(int) * Nn;
    int*   deg    = (int*)ws;     ws += sizeof(int) * Nn;
    float* dinv   = (float*)ws;   ws += sizeof(float) * Nn;
    float* pooled = (float*)ws;   ws += sizeof(float) * Gg * Hh;   // cnt follows directly
    int*   cnt    = (int*)ws;     ws += sizeof(int) * Gg;

    int* perm = (int*)bucket;   // alias: bucket dead after k_build
    int* M2   = M;              // alias: M dead after k_bucket (DB*256 <= NCH*NR)

    const int nbNode16 = (Nn + 15) / 16;                   // 6250
    const int nbTile   = (Nn + TM - 1) / TM;               // 1563

    // ---- graph preprocessing: counting sort -> CSR, deg, dinv, rowptr ----
    k_count <<<NCH, 512, 0, stream>>>(dst, M);
    k_scanM <<<NR, 256, 0, stream>>>(M, T);
    k_scanT <<<1, 512, 0, stream>>>(T, R);
    k_bucket<<<NCH, 512, 0, stream>>>(src, dst, M, R, bucket);
    k_build <<<NR, 512, 0, stream>>>(bucket, R, csr, rowptr, deg, dinv);

    // ---- degree-binned node permutation (for the 3 k_aggemm) ----
    k_dhist <<<DB, 256, 0, stream>>>(deg, M2);
    k_dscan <<<1, 256, 0, stream>>>(M2);
    k_dperm <<<DB, 256, 0, stream>>>(deg, M2, perm);

    // ---- layer 1 GEMM (MFMA; also zeroes hl pad row) ----
    k_gemm128<<<nbTile, 256, 0, stream>>>(x, W1, dinv, hl);

    // ---- zero pooled + cnt (adjacent -> one memset) ----
    hipMemsetAsync(pooled, 0, sizeof(float) * Gg * Hh + sizeof(int) * Gg, stream);

    // ---- layers 1..3 aggregation fused with next layer's GEMM ----
    k_aggemm<<<nbNode16, 256, 0, stream>>>(hl, csr, rowptr, deg, dinv, b1, W2, perm, hbuf);
    k_aggemm<<<nbNode16, 256, 0, stream>>>(hbuf, csr, rowptr, deg, dinv, b2, W3, perm, hl);
    k_aggemm<<<nbNode16, 256, 0, stream>>>(hl, csr, rowptr, deg, dinv, b3, W4, perm, hbuf);

    // ---- layer 4 aggregation fused with mean-pool ----
    k_aggpool<<<nbNode16, 256, 0, stream>>>(hbuf, csr, rowptr, deg, dinv, b4,
                                            batch, pooled, cnt);

    // ---- head ----
    k_head<<<1, 256, 0, stream>>>(pooled, cnt, Wf1, bf1, Wf2, bf2, out);
}

// Round 21
// 174.939 us; speedup vs baseline: 1.0931x; 1.0931x over previous
//
#include <hip/hip_runtime.h>
#include <hip/hip_bf16.h>
#include <hip/hip_fp8.h>

// Problem constants (fixed by the reference)
constexpr int Nn  = 100000;   // nodes
constexpr int Ee  = 1600000;  // edges
constexpr int FIN = 128;      // input features
constexpr int Hh  = 32;       // hidden
constexpr int Cc  = 10;       // classes
constexpr int Gg  = 256;      // graphs

// Two-level counting sort: ranges of 256 nodes, chunks of 8192 edges.
constexpr int RSH  = 8;                          // range shift (256 nodes)
constexpr int NR   = (Nn + 255) >> RSH;          // 391 ranges
constexpr int CHSZ = 8192;                       // edges per chunk
constexpr int NCH  = (Ee + CHSZ - 1) / CHSZ;     // 196 chunks

typedef __attribute__((ext_vector_type(8))) short bf16x8;
typedef __attribute__((ext_vector_type(4))) float f32x4;

__device__ __forceinline__ void atomAddF(float* p, float v) {
    unsafeAtomicAdd(p, v);    // HW global_atomic_add_f32 on gfx950
}

__device__ __forceinline__ short f2bfbits(float v) {
    __hip_bfloat16 h = __float2bfloat16(v);
    return __builtin_bit_cast(short, h);
}

// fp8 e4m3 storage (OCP on gfx950): table rows are 32 B (32 x fp8).
__device__ __forceinline__ void fp8pair(unsigned short u, float& lo, float& hi) {
#if __has_builtin(__builtin_amdgcn_cvt_f32_fp8)
    lo = __builtin_amdgcn_cvt_f32_fp8((int)u, 0);
    hi = __builtin_amdgcn_cvt_f32_fp8((int)u, 1);
#else
    __hip_fp8_e4m3 a, b;
    a.__x = (unsigned char)(u & 0xff);
    b.__x = (unsigned char)(u >> 8);
    lo = (float)a; hi = (float)b;
#endif
}
__device__ __forceinline__ unsigned char ftofp8(float f) {
    __hip_fp8_e4m3 v(f);
    return (unsigned char)v.__x;
}

// ---------- S1: per-chunk histogram over node ranges ----------
__global__ __launch_bounds__(512) void k_count(const int* __restrict__ dst,
                                               int* __restrict__ M) {
    __shared__ int hist[NR];
    int c = blockIdx.x;
    for (int i = threadIdx.x; i < NR; i += 512) hist[i] = 0;
    __syncthreads();
    int e0 = c * CHSZ, e1 = min(e0 + CHSZ, Ee);
    const int4* d4 = reinterpret_cast<const int4*>(dst + e0);
    int n4 = (e1 - e0) >> 2;
    for (int i = threadIdx.x; i < n4; i += 512) {
        int4 d = d4[i];
        atomicAdd(&hist[d.x >> RSH], 1);
        atomicAdd(&hist[d.y >> RSH], 1);
        atomicAdd(&hist[d.z >> RSH], 1);
        atomicAdd(&hist[d.w >> RSH], 1);
    }
    __syncthreads();
    for (int i = threadIdx.x; i < NR; i += 512) M[c * NR + i] = hist[i];
}

// ---------- S2a: per-range exclusive scan over chunks (in place), totals -> T
__global__ __launch_bounds__(256) void k_scanM(int* __restrict__ M,
                                               int* __restrict__ T) {
    __shared__ int sh[256];
    int t = threadIdx.x, r = blockIdx.x;
    int v = (t < NCH) ? M[t * NR + r] : 0;
    sh[t] = v;
    __syncthreads();
    for (int off = 1; off < 256; off <<= 1) {
        int x = (t >= off) ? sh[t - off] : 0;
        __syncthreads();
        sh[t] += x;
        __syncthreads();
    }
    if (t < NCH) M[t * NR + r] = sh[t] - v;   // exclusive
    if (t == 255) T[r] = sh[255];
}

// ---------- S2b: exclusive scan of range totals -> R (R[NR] = Ee) ----------
__global__ __launch_bounds__(512) void k_scanT(const int* __restrict__ T,
                                               int* __restrict__ R) {
    __shared__ int sh[512];
    int t = threadIdx.x;
    int v = (t < NR) ? T[t] : 0;
    sh[t] = v;
    __syncthreads();
    for (int off = 1; off < 512; off <<= 1) {
        int x = (t >= off) ? sh[t - off] : 0;
        __syncthreads();
        sh[t] += x;
        __syncthreads();
    }
    if (t < NR) R[t] = sh[t] - v;
    if (t == 511) R[NR] = sh[511];
}

// ---------- S3: scatter packed (localdst<<17 | src) into range bucket ----------
__global__ __launch_bounds__(512) void k_bucket(const int* __restrict__ src,
                                                const int* __restrict__ dst,
                                                const int* __restrict__ M,
                                                const int* __restrict__ R,
                                                unsigned* __restrict__ bucket) {
    __shared__ int cur[NR];
    int c = blockIdx.x;
    for (int i = threadIdx.x; i < NR; i += 512) cur[i] = M[c * NR + i] + R[i];
    __syncthreads();
    int e0 = c * CHSZ, e1 = min(e0 + CHSZ, Ee);
    const int4* d4 = reinterpret_cast<const int4*>(dst + e0);
    const int4* s4 = reinterpret_cast<const int4*>(src + e0);
    int n4 = (e1 - e0) >> 2;
    for (int i = threadIdx.x; i < n4; i += 512) {
        int4 d = d4[i];
        int4 s = s4[i];
        int sl;
        sl = atomicAdd(&cur[d.x >> RSH], 1); bucket[sl] = ((unsigned)(d.x & 255) << 17) | (unsigned)s.x;
        sl = atomicAdd(&cur[d.y >> RSH], 1); bucket[sl] = ((unsigned)(d.y & 255) << 17) | (unsigned)s.y;
        sl = atomicAdd(&cur[d.z >> RSH], 1); bucket[sl] = ((unsigned)(d.z & 255) << 17) | (unsigned)s.z;
        sl = atomicAdd(&cur[d.w >> RSH], 1); bucket[sl] = ((unsigned)(d.w & 255) << 17) | (unsigned)s.w;
    }
}

// ---------- S4: per-range CSR build + deg + dinv + rowptr ----------
__global__ __launch_bounds__(512) void k_build(const unsigned* __restrict__ bucket,
                                               const int* __restrict__ R,
                                               int* __restrict__ csr,
                                               int* __restrict__ rowptr,
                                               int* __restrict__ deg,
                                               float* __restrict__ dinv) {
    __shared__ int hist[256];
    __shared__ int scn[256];
    __shared__ int cur[256];
    int t = threadIdx.x, r = blockIdx.x;
    int lo = r << RSH;
    int cnt = min(256, Nn - lo);
    int b0 = R[r], b1 = R[r + 1];
    if (t < 256) hist[t] = 0;
    __syncthreads();
    for (int i = b0 + t; i < b1; i += 512) {
        unsigned e = bucket[i];
        atomicAdd(&hist[e >> 17], 1);
    }
    __syncthreads();
    int hv = (t < 256) ? hist[t] : 0;
    if (t < 256) scn[t] = hv;
    __syncthreads();
    for (int off = 1; off < 256; off <<= 1) {
        int x = 0;
        if (t < 256 && t >= off) x = scn[t - off];
        __syncthreads();
        if (t < 256) scn[t] += x;
        __syncthreads();
    }
    if (t < cnt) {
        int base = b0 + (scn[t] - hv);   // exclusive within range + range start
        rowptr[lo + t] = base;
        deg[lo + t] = hv;
        dinv[lo + t] = rsqrtf((float)hv + 1.0f);
        cur[t] = base;
    }
    __syncthreads();
    for (int i = b0 + t; i < b1; i += 512) {
        unsigned e = bucket[i];
        int sl = atomicAdd(&cur[e >> 17], 1);
        csr[sl] = (int)(e & 0x1FFFFu);
    }
}

// ---------- layer-1 GEMM via bf16 MFMA (no LDS, no syncthreads), fp8 out ----
constexpr int TM = 64;
__global__ __launch_bounds__(256) void k_gemm128(const float* __restrict__ x,
                                                 const float* __restrict__ W,
                                                 const float* __restrict__ dinv,
                                                 unsigned char* __restrict__ hls) {
    int tid  = threadIdx.x;
    int wave = tid >> 6;
    int lane = tid & 63;
    int lrow = lane & 15;
    int koct = lane >> 4;                       // 0..3
    int row0 = blockIdx.x * TM + wave * 16;
    int gr   = row0 + lrow;
    int grc  = (gr < Nn) ? gr : (Nn - 1);       // clamped load row

    // B fragments: 2 col-tiles x 4 K-steps, lane holds W[kb+j][ct*16+lrow]
    bf16x8 bfrag[2][4];
#pragma unroll
    for (int s = 0; s < 4; ++s) {
        int kb = s * 32 + koct * 8;
#pragma unroll
        for (int ct = 0; ct < 2; ++ct) {
            int col = ct * 16 + lrow;
            bf16x8 bb;
#pragma unroll
            for (int j = 0; j < 8; ++j) bb[j] = f2bfbits(W[(kb + j) * Hh + col]);
            bfrag[ct][s] = bb;
        }
    }

    f32x4 acc0 = {0.f, 0.f, 0.f, 0.f};
    f32x4 acc1 = {0.f, 0.f, 0.f, 0.f};
    const float4* xrow = reinterpret_cast<const float4*>(x + (size_t)grc * FIN);
#pragma unroll
    for (int s = 0; s < 4; ++s) {
        int kb = s * 32 + koct * 8;             // f4 index = kb/4
        float4 v0 = xrow[kb / 4];
        float4 v1 = xrow[kb / 4 + 1];
        bf16x8 af;
        af[0] = f2bfbits(v0.x); af[1] = f2bfbits(v0.y);
        af[2] = f2bfbits(v0.z); af[3] = f2bfbits(v0.w);
        af[4] = f2bfbits(v1.x); af[5] = f2bfbits(v1.y);
        af[6] = f2bfbits(v1.z); af[7] = f2bfbits(v1.w);
        acc0 = __builtin_amdgcn_mfma_f32_16x16x32_bf16(af, bfrag[0][s], acc0, 0, 0, 0);
        acc1 = __builtin_amdgcn_mfma_f32_16x16x32_bf16(af, bfrag[1][s], acc1, 0, 0, 0);
    }

    // write back: row = row0 + (lane>>4)*4 + r, cols lrow and lrow+16 (fp8)
    int crow0 = row0 + koct * 4;
#pragma unroll
    for (int r = 0; r < 4; ++r) {
        int rr = crow0 + r;
        if (rr < Nn) {
            float d = dinv[rr];
            hls[(size_t)rr * Hh + lrow]      = ftofp8(acc0[r] * d);
            hls[(size_t)rr * Hh + 16 + lrow] = ftofp8(acc1[r] * d);
        } else if (rr == Nn) {                  // zero pad row
            hls[(size_t)Nn * Hh + lrow]      = 0;
            hls[(size_t)Nn * Hh + 16 + lrow] = 0;
        }
    }
}

// ---------- fused aggregation + next-layer GEMM (fp8 tables) ----------
// 16 lanes/node, each lane owns cols (2l, 2l+1) as one packed fp8x2 ushort.
// MLP=16; masked lanes gather the zeroed pad row Nn. Table = 3.2 MB -> fits
// each XCD's 4 MB L2. Plain cached loads (round 14: nontemporal breaks L2
// retention). Natural node order (round 20: degree-permuted order broke
// write coalescing + csr locality, -16 us). Proven round-16 structure.
__global__ __launch_bounds__(256) void k_aggemm(const unsigned char* __restrict__ hls,
                                                const int* __restrict__ csr,
                                                const int* __restrict__ rowptr,
                                                const int* __restrict__ deg,
                                                const float* __restrict__ dinv,
                                                const float* __restrict__ b,
                                                const float* __restrict__ Wn,
                                                unsigned char* __restrict__ hout) {
    __shared__ float ws[Hh * Hh];
    int tid = threadIdx.x;
    ws[tid]       = Wn[tid];
    ws[tid + 256] = Wn[tid + 256];
    ws[tid + 512] = Wn[tid + 512];
    ws[tid + 768] = Wn[tid + 768];
    if (blockIdx.x == 0 && tid < 16)   // zero pad row of output table
        reinterpret_cast<unsigned short*>(hout)[Nn * 16 + tid] = 0;
    __syncthreads();
    int n = blockIdx.x * 16 + (tid >> 4);
    int l = tid & 15;
    const unsigned short* h16 = reinterpret_cast<const unsigned short*>(hls);
    int beg = rowptr[n];
    int end = beg + deg[n];
    float a0 = 0.f, a1 = 0.f;
    for (int i = beg; i < end; i += 16) {
        int idx[16];
#pragma unroll
        for (int j = 0; j < 16; ++j) {
            int k = i + j;
            int c = csr[k];                 // csr padded by 16 -> in-bounds
            idx[j] = (k < end) ? c : Nn;    // Nn = zeroed pad row
        }
        unsigned short v[16];
#pragma unroll
        for (int j = 0; j < 16; ++j) v[j] = h16[idx[j] * 16 + l];
#pragma unroll
        for (int j = 0; j < 16; ++j) {
            float lo, hi;
            fp8pair(v[j], lo, hi);
            a0 += lo;
            a1 += hi;
        }
    }
    float di = dinv[n];
    float s0, s1;
    fp8pair(h16[n * 16 + l], s0, s1);
    int c0 = 2 * l, c1 = 2 * l + 1;
    float h0 = fmaxf(fmaf(di, a0 + s0, b[c0]), 0.f);
    float h1 = fmaxf(fmaf(di, a1 + s1, b[c1]), 0.f);
    // micro-GEMM: o[c] = sum_k h_k * Wn[k][c]; h_{2m},h_{2m+1} live in lane m
    float o0 = 0.f, o1 = 0.f;
#pragma unroll
    for (int m = 0; m < 16; ++m) {
        float hk0 = __shfl(h0, m, 16);
        float hk1 = __shfl(h1, m, 16);
        o0 = fmaf(hk0, ws[(2 * m) * Hh + c0], o0);
        o0 = fmaf(hk1, ws[(2 * m + 1) * Hh + c0], o0);
        o1 = fmaf(hk0, ws[(2 * m) * Hh + c1], o1);
        o1 = fmaf(hk1, ws[(2 * m + 1) * Hh + c1], o1);
    }
    unsigned short packed = (unsigned short)ftofp8(o0 * di) |
                            ((unsigned short)ftofp8(o1 * di) << 8);
    reinterpret_cast<unsigned short*>(hout)[n * 16 + l] = packed;
}

// ---------- final aggregation fused with mean-pool (fp8 table in) ----------
__global__ __launch_bounds__(256) void k_aggpool(const unsigned char* __restrict__ hls,
                                                 const int* __restrict__ csr,
                                                 const int* __restrict__ rowptr,
                                                 const int* __restrict__ deg,
                                                 const float* __restrict__ dinv,
                                                 const float* __restrict__ b,
                                                 const int* __restrict__ batch,
                                                 float* __restrict__ pooled,
                                                 int* __restrict__ cnt) {
    __shared__ float hsh[16 * 34];   // stride 34 to spread banks
    __shared__ int   gsh[16];
    int tid = threadIdx.x;
    int nd = tid >> 4;
    int n = blockIdx.x * 16 + nd;
    int l = tid & 15;
    const unsigned short* h16 = reinterpret_cast<const unsigned short*>(hls);
    int beg = rowptr[n];
    int end = beg + deg[n];
    float a0 = 0.f, a1 = 0.f;
    for (int i = beg; i < end; i += 16) {
        int idx[16];
#pragma unroll
        for (int j = 0; j < 16; ++j) {
            int k = i + j;
            int c = csr[k];
            idx[j] = (k < end) ? c : Nn;
        }
        unsigned short v[16];
#pragma unroll
        for (int j = 0; j < 16; ++j) v[j] = h16[idx[j] * 16 + l];
#pragma unroll
        for (int j = 0; j < 16; ++j) {
            float lo, hi;
            fp8pair(v[j], lo, hi);
            a0 += lo;
            a1 += hi;
        }
    }
    float di = dinv[n];
    float s0, s1;
    fp8pair(h16[n * 16 + l], s0, s1);
    float h0 = fmaxf(fmaf(di, a0 + s0, b[2 * l]), 0.f);
    float h1 = fmaxf(fmaf(di, a1 + s1, b[2 * l + 1]), 0.f);
    hsh[nd * 34 + 2 * l]     = h0;
    hsh[nd * 34 + 2 * l + 1] = h1;
    if (l == 0) gsh[nd] = batch[n];
    __syncthreads();
    if (tid < 32) {           // segmented flush: col = tid
        int col = tid;
        float acc = 0.f;
        int gcur = gsh[0];
#pragma unroll
        for (int k = 0; k < 16; ++k) {
            int g = gsh[k];
            if (g != gcur) {
                atomAddF(&pooled[gcur * Hh + col], acc);
                acc = 0.f; gcur = g;
            }
            acc += hsh[k * 34 + col];
        }
        atomAddF(&pooled[gcur * Hh + col], acc);
    } else if (tid == 32) {   // node counts
        int gcur = gsh[0], run = 0;
#pragma unroll
        for (int k = 0; k < 16; ++k) {
            int g = gsh[k];
            if (g != gcur) { atomicAdd(&cnt[gcur], run); run = 0; gcur = g; }
            run++;
        }
        atomicAdd(&cnt[gcur], run);
    }
}

// ---------- MLP head + log_softmax ----------
__global__ __launch_bounds__(256) void k_head(const float* __restrict__ pooled,
                                              const int* __restrict__ cnt,
                                              const float* __restrict__ Wf1,
                                              const float* __restrict__ bf1,
                                              const float* __restrict__ Wf2,
                                              const float* __restrict__ bf2,
                                              float* __restrict__ out) {
    __shared__ float w1[Hh * Hh];
    __shared__ float w2[Hh * Cc];
    __shared__ float sb1[Hh];
    __shared__ float sb2[Cc];
    int tid = threadIdx.x;
    w1[tid] = Wf1[tid]; w1[tid + 256] = Wf1[tid + 256];
    w1[tid + 512] = Wf1[tid + 512]; w1[tid + 768] = Wf1[tid + 768];
    for (int i = tid; i < Hh * Cc; i += 256) w2[i] = Wf2[i];
    if (tid < Hh) sb1[tid] = bf1[tid];
    if (tid < Cc) sb2[tid] = bf2[tid];
    __syncthreads();

    int g = tid;
    float inv = 1.0f / fmaxf((float)cnt[g], 1.0f);
    float p[Hh];
#pragma unroll
    for (int c = 0; c < Hh; ++c) p[c] = pooled[g * Hh + c] * inv;
    float h1[Hh];
#pragma unroll
    for (int j = 0; j < Hh; ++j) {
        float acc = sb1[j];
#pragma unroll
        for (int k = 0; k < Hh; ++k) acc = fmaf(p[k], w1[k * Hh + j], acc);
        h1[j] = fmaxf(acc, 0.f);
    }
    float lg[Cc];
#pragma unroll
    for (int j = 0; j < Cc; ++j) {
        float acc = sb2[j];
#pragma unroll
        for (int k = 0; k < Hh; ++k) acc = fmaf(h1[k], w2[k * Cc + j], acc);
        lg[j] = acc;
    }
    float m = lg[0];
#pragma unroll
    for (int j = 1; j < Cc; ++j) m = fmaxf(m, lg[j]);
    float s = 0.f;
#pragma unroll
    for (int j = 0; j < Cc; ++j) s += __expf(lg[j] - m);
    float lse = m + __logf(s);
#pragma unroll
    for (int j = 0; j < Cc; ++j) out[g * Cc + j] = lg[j] - lse;
}

extern "C" void kernel_launch(void* const* d_in, const int* in_sizes, int n_in,
                              void* d_out, int out_size, void* d_ws, size_t ws_size,
                              hipStream_t stream) {
    const float* x    = (const float*)d_in[0];
    const int*   ei   = (const int*)d_in[1];   // [2, E] -> src = ei, dst = ei + E
    const int*   batch= (const int*)d_in[2];
    const float* W1   = (const float*)d_in[3];
    const float* b1   = (const float*)d_in[4];
    const float* W2   = (const float*)d_in[5];
    const float* b2   = (const float*)d_in[6];
    const float* W3   = (const float*)d_in[7];
    const float* b3   = (const float*)d_in[8];
    const float* W4   = (const float*)d_in[9];
    const float* b4   = (const float*)d_in[10];
    const float* Wf1  = (const float*)d_in[11];
    const float* bf1  = (const float*)d_in[12];
    const float* Wf2  = (const float*)d_in[13];
    const float* bf2  = (const float*)d_in[14];
    float* out = (float*)d_out;

    const int* src = ei;
    const int* dst = ei + Ee;

    // Workspace layout (8B-aligned first). Feature tables are fp8 (32 B/row,
    // 3.2 MB -> L2-resident per XCD) with a zeroed pad row at index Nn.
    char* ws = (char*)d_ws;
    unsigned* bucket = (unsigned*)ws; ws += sizeof(unsigned) * Ee;           // 6.4 MB
    unsigned char* hl   = (unsigned char*)ws; ws += (size_t)(Nn + 1) * Hh;   // 3.2 MB
    unsigned char* hbuf = (unsigned char*)ws; ws += (size_t)(Nn + 1) * Hh;   // 3.2 MB
    int*   csr    = (int*)ws;     ws += sizeof(int) * (Ee + 16);             // +16 pad
    int*   M      = (int*)ws;     ws += sizeof(int) * NCH * NR;              // 306 KB
    int*   T      = (int*)ws;     ws += sizeof(int) * NR;
    int*   R      = (int*)ws;     ws += sizeof(int) * (NR + 1);
    int*   rowptr = (int*)ws;     ws += sizeof(int) * Nn;
    int*   deg    = (int*)ws;     ws += sizeof(int) * Nn;
    float* dinv   = (float*)ws;   ws += sizeof(float) * Nn;
    float* pooled = (float*)ws;   ws += sizeof(float) * Gg * Hh;   // cnt follows directly
    int*   cnt    = (int*)ws;     ws += sizeof(int) * Gg;

    const int nbNode16 = (Nn + 15) / 16;                   // 6250
    const int nbTile   = (Nn + TM - 1) / TM;               // 1563

    // ---- graph preprocessing: counting sort -> CSR, deg, dinv, rowptr ----
    k_count <<<NCH, 512, 0, stream>>>(dst, M);
    k_scanM <<<NR, 256, 0, stream>>>(M, T);
    k_scanT <<<1, 512, 0, stream>>>(T, R);
    k_bucket<<<NCH, 512, 0, stream>>>(src, dst, M, R, bucket);
    k_build <<<NR, 512, 0, stream>>>(bucket, R, csr, rowptr, deg, dinv);

    // ---- layer 1 GEMM (MFMA; also zeroes hl pad row) ----
    k_gemm128<<<nbTile, 256, 0, stream>>>(x, W1, dinv, hl);

    // ---- zero pooled + cnt (adjacent -> one memset) ----
    hipMemsetAsync(pooled, 0, sizeof(float) * Gg * Hh + sizeof(int) * Gg, stream);

    // ---- layers 1..3 aggregation fused with next layer's GEMM ----
    k_aggemm<<<nbNode16, 256, 0, stream>>>(hl, csr, rowptr, deg, dinv, b1, W2, hbuf);
    k_aggemm<<<nbNode16, 256, 0, stream>>>(hbuf, csr, rowptr, deg, dinv, b2, W3, hl);
    k_aggemm<<<nbNode16, 256, 0, stream>>>(hl, csr, rowptr, deg, dinv, b3, W4, hbuf);

    // ---- layer 4 aggregation fused with mean-pool ----
    k_aggpool<<<nbNode16, 256, 0, stream>>>(hbuf, csr, rowptr, deg, dinv, b4,
                                            batch, pooled, cnt);

    // ---- head ----
    k_head<<<1, 256, 0, stream>>>(pooled, cnt, Wf1, bf1, Wf2, bf2, out);
}